// Round 6
// baseline (2766.416 us; speedup 1.0000x reference)
//
#include <hip/hip_runtime.h>
#include <math.h>

// ===========================================================================
// Stage 1: conv1(5x5,pad1) + ReLU + BN(eval) + maxpool(3,2,1, zero-pad)
//   in : x [512,3,128,128]   out: out1 [512,5,63,63]
//   w(o,c,ki,kj) = k1[((c*5+ki)*5+kj)*5 + o]   (reference reshape semantics)
// Row-pass structure: for each of the 3 conv rows of the pool window, compute
// acc[3 cols][5 ch] fully unrolled (static LDS offsets, scalar-side weights),
// fold into m[5] via relu->BN->max. VGPR budget <=64 -> 8 waves/SIMD.
// cr loop kept ROLLED (code size ~10KB, I-cache friendly).
// ===========================================================================
__global__ __launch_bounds__(256, 8) void conv1_pool_kernel(
    const float* __restrict__ x, const float* __restrict__ k1,
    const float* __restrict__ gamma, const float* __restrict__ beta,
    float* __restrict__ out1)
{
    const int b    = blockIdx.y;
    const int tile = blockIdx.x;          // 0..15
    const int ty = tile >> 2, tx = tile & 3;
    const int tid = threadIdx.x;

    __shared__ __align__(16) float sIn[3][37][38];   // 16.9 KB, 8 blocks/CU

    const int iy0 = 32 * ty - 2, ix0 = 32 * tx - 2;
    for (int idx = tid; idx < 3 * 37 * 37; idx += 256) {
        int c  = idx / 1369;
        int r  = idx - c * 1369;
        int ly = r / 37, lx = r - ly * 37;
        int gy = iy0 + ly, gx = ix0 + lx;
        float v = 0.f;
        if ((unsigned)gy < 128u && (unsigned)gx < 128u)
            v = x[((b * 3 + c) * 128 + gy) * 128 + gx];
        sIn[c][ly][lx] = v;
    }
    __syncthreads();

    const int lpy = tid >> 4, lpx = tid & 15;
    const int py = 16 * ty + lpy, px = 16 * tx + lpx;
    const int x0 = 2 * lpx;                // even -> 8B aligned

    const float invs = rsqrtf(1.0f + 1e-5f);
    float sc[5], bt[5];
#pragma unroll
    for (int o = 0; o < 5; ++o) { sc[o] = gamma[o] * invs; bt[o] = beta[o]; }

    float m[5];
#pragma unroll
    for (int o = 0; o < 5; ++o) m[o] = -3.4e38f;

    const bool pxok = (px > 0);

#pragma unroll 1                            // keep rolled: 3 passes
    for (int cr = 0; cr < 3; ++cr) {
        float acc[3][5];
#pragma unroll
        for (int p = 0; p < 3; ++p)
#pragma unroll
            for (int o = 0; o < 5; ++o) acc[p][o] = 0.f;

#pragma unroll
        for (int c = 0; c < 3; ++c)
#pragma unroll
            for (int ki = 0; ki < 5; ++ki) {
                const float* row = &sIn[c][2 * lpy + cr + ki][x0];
                float2 v01 = *(const float2*)(row);
                float2 v23 = *(const float2*)(row + 2);
                float2 v45 = *(const float2*)(row + 4);
                float  v6  = row[6];
                float iv[7] = {v01.x, v01.y, v23.x, v23.y, v45.x, v45.y, v6};
#pragma unroll
                for (int kj = 0; kj < 5; ++kj) {
                    const float* w = &k1[((c * 5 + ki) * 5 + kj) * 5];
#pragma unroll
                    for (int p = 0; p < 3; ++p) {
                        float v = iv[p + kj];
#pragma unroll
                        for (int o = 0; o < 5; ++o)
                            acc[p][o] = fmaf(v, w[o], acc[p][o]);
                    }
                }
            }

        // fold this conv row into the pool max (relu -> BN -> max)
        const bool rowok = (py + cr > 0);   // conv row 2py-1+cr >= 0
#pragma unroll
        for (int p = 0; p < 3; ++p) {
            const bool ok = rowok && (p > 0 || pxok);
#pragma unroll
            for (int o = 0; o < 5; ++o) {
                float v = fmaf(fmaxf(acc[p][o], 0.f), sc[o], bt[o]);
                m[o] = ok ? fmaxf(m[o], v) : m[o];
            }
        }
    }

    if (py < 63 && px < 63) {
        const bool edge = (py == 0 || px == 0);
#pragma unroll
        for (int o = 0; o < 5; ++o) {
            float v = edge ? fmaxf(m[o], 0.f) : m[o];   // pool zero-pad
            out1[((b * 5 + o) * 63 + py) * 63 + px] = v;
        }
    }
}

// ===========================================================================
// Stage 2: conv2(3x3,pad1) + ReLU + maxpool(3,2,1)
//   in : out1 [512,5,63,63]  out: out2 [512,9,32,32]
//   w(o,c,ki,kj) = k2[((c*3+ki)*3+kj)*9 + o]
// Same row-pass structure. m init 0 handles ALL pool pads exactly (relu>=0,
// pads are zeros); invalid conv rows/cols (cy==-1 or 63, cx==-1 or 63)
// simply don't update m.
// ===========================================================================
__global__ __launch_bounds__(256, 8) void conv2_pool_kernel(
    const float* __restrict__ in1, const float* __restrict__ k2,
    float* __restrict__ out2)
{
    const int b    = blockIdx.y;
    const int tile = blockIdx.x;          // 0..3
    const int ty = tile >> 1, tx = tile & 1;
    const int tid = threadIdx.x;

    __shared__ __align__(16) float sIn[5][35][36];   // 25.9 KB, 6 blocks/CU

    const int iy0 = 32 * ty - 2, ix0 = 32 * tx - 2;
    for (int idx = tid; idx < 5 * 35 * 35; idx += 256) {
        int c  = idx / 1225;
        int r  = idx - c * 1225;
        int ly = r / 35, lx = r - ly * 35;
        int gy = iy0 + ly, gx = ix0 + lx;
        float v = 0.f;
        if ((unsigned)gy < 63u && (unsigned)gx < 63u)
            v = in1[((b * 5 + c) * 63 + gy) * 63 + gx];
        sIn[c][ly][lx] = v;
    }
    __syncthreads();

    const int lpy = tid >> 4, lpx = tid & 15;
    const int py = 16 * ty + lpy, px = 16 * tx + lpx;   // 0..31
    const int x0 = 2 * lpx;

    float m[9];
#pragma unroll
    for (int o = 0; o < 9; ++o) m[o] = 0.f;

    const bool pxok = (px > 0);
    const bool pxhi = (px < 31);

#pragma unroll 1                            // keep rolled: 3 passes
    for (int cr = 0; cr < 3; ++cr) {
        float acc[3][9];
#pragma unroll
        for (int p = 0; p < 3; ++p)
#pragma unroll
            for (int o = 0; o < 9; ++o) acc[p][o] = 0.f;

#pragma unroll
        for (int c = 0; c < 5; ++c)
#pragma unroll
            for (int ki = 0; ki < 3; ++ki) {
                const float* row = &sIn[c][2 * lpy + cr + ki][x0];
                float2 v01 = *(const float2*)(row);
                float2 v23 = *(const float2*)(row + 2);
                float  v4  = row[4];
                float iv[5] = {v01.x, v01.y, v23.x, v23.y, v4};
#pragma unroll
                for (int kj = 0; kj < 3; ++kj) {
                    const float* w = &k2[((c * 3 + ki) * 3 + kj) * 9];
#pragma unroll
                    for (int p = 0; p < 3; ++p) {
                        float v = iv[p + kj];
#pragma unroll
                        for (int o = 0; o < 9; ++o)
                            acc[p][o] = fmaf(v, w[o], acc[p][o]);
                    }
                }
            }

        // conv row cy = 2py-1+cr valid iff 0 <= cy < 63
        const int cy = 2 * py - 1 + cr;
        const bool rowok = ((unsigned)cy < 63u);
#pragma unroll
        for (int p = 0; p < 3; ++p) {
            const bool ok = rowok && (p > 0 || pxok) && (p < 2 || pxhi);
#pragma unroll
            for (int o = 0; o < 9; ++o) {
                float v = fmaxf(acc[p][o], 0.f);      // relu; pads stay 0
                m[o] = ok ? fmaxf(m[o], v) : m[o];
            }
        }
    }

#pragma unroll
    for (int o = 0; o < 9; ++o)
        out2[((b * 9 + o) * 32 + py) * 32 + px] = m[o];
}

// ===========================================================================
// Stage 3: conv3(3x3,pad1) + flatten + FC(16384->6) + softmax, per sample.
//   1024 threads, one conv pixel each.
//   w(o,c,ki,kj) = k3[((c*3+ki)*3+kj)*16 + o]
// ===========================================================================
__global__ __launch_bounds__(1024) void conv3_fc_kernel(
    const float* __restrict__ in2, const float* __restrict__ k3,
    const float* __restrict__ fcw, const float* __restrict__ fcb,
    float* __restrict__ out)
{
    const int b   = blockIdx.x;
    const int tid = threadIdx.x;

    __shared__ float sP[9][34][36];   // zero-padded border
    __shared__ float sRed[16][6];

    for (int idx = tid; idx < 9 * 34 * 36; idx += 1024) {
        int c  = idx / (34 * 36);
        int r  = idx - c * (34 * 36);
        int yy = r / 36, xx = r - yy * 36;
        float v = 0.f;
        if (yy >= 1 && yy < 33 && xx >= 1 && xx < 33)
            v = in2[((b * 9 + c) * 32 + (yy - 1)) * 32 + (xx - 1)];
        sP[c][yy][xx] = v;
    }
    __syncthreads();

    const int s = tid;                 // spatial index 0..1023
    const int y = s >> 5, xc = s & 31;

    float acc16[16];
#pragma unroll
    for (int o = 0; o < 16; ++o) acc16[o] = 0.f;

#pragma unroll
    for (int c = 0; c < 9; ++c)
#pragma unroll
        for (int ki = 0; ki < 3; ++ki) {
            float iv[3];
#pragma unroll
            for (int j = 0; j < 3; ++j) iv[j] = sP[c][y + ki][xc + j];
#pragma unroll
            for (int kj = 0; kj < 3; ++kj) {
                float v = iv[kj];
                const float* w = &k3[((c * 3 + ki) * 3 + kj) * 16];
#pragma unroll
                for (int o = 0; o < 16; ++o)
                    acc16[o] = fmaf(v, w[o], acc16[o]);
            }
        }

    float acc6[6] = {0.f, 0.f, 0.f, 0.f, 0.f, 0.f};
#pragma unroll
    for (int o = 0; o < 16; ++o) {
        const int f = o * 1024 + s;
#pragma unroll
        for (int cls = 0; cls < 6; ++cls)
            acc6[cls] = fmaf(acc16[o], fcw[cls * 16384 + f], acc6[cls]);
    }

#pragma unroll
    for (int cls = 0; cls < 6; ++cls) {
        float v = acc6[cls];
#pragma unroll
        for (int off = 32; off >= 1; off >>= 1)
            v += __shfl_xor(v, off, 64);
        if ((tid & 63) == 0) sRed[tid >> 6][cls] = v;
    }
    __syncthreads();
    if (tid == 0) {
        float logits[6], mxl = -3.4e38f;
#pragma unroll
        for (int cls = 0; cls < 6; ++cls) {
            float l = fcb[cls];
            for (int wv = 0; wv < 16; ++wv) l += sRed[wv][cls];
            logits[cls] = l;
            mxl = fmaxf(mxl, l);
        }
        float ssum = 0.f;
#pragma unroll
        for (int cls = 0; cls < 6; ++cls) {
            logits[cls] = expf(logits[cls] - mxl);
            ssum += logits[cls];
        }
#pragma unroll
        for (int cls = 0; cls < 6; ++cls)
            out[b * 6 + cls] = logits[cls] / ssum;
    }
}

extern "C" void kernel_launch(void* const* d_in, const int* in_sizes, int n_in,
                              void* d_out, int out_size, void* d_ws, size_t ws_size,
                              hipStream_t stream)
{
    const float* x     = (const float*)d_in[0];
    const float* k1    = (const float*)d_in[1];
    const float* gamma = (const float*)d_in[2];
    const float* beta  = (const float*)d_in[3];
    const float* k2    = (const float*)d_in[4];
    const float* k3    = (const float*)d_in[5];
    const float* fcw   = (const float*)d_in[6];
    const float* fcb   = (const float*)d_in[7];
    float* out = (float*)d_out;

    float* out1 = (float*)d_ws;                       // 512*5*63*63  (40.6 MB)
    float* out2 = out1 + (size_t)512 * 5 * 63 * 63;   // 512*9*32*32  (18.9 MB)

    conv1_pool_kernel<<<dim3(16, 512), 256, 0, stream>>>(x, k1, gamma, beta, out1);
    conv2_pool_kernel<<<dim3(4, 512), 256, 0, stream>>>(out1, k2, out2);
    conv3_fc_kernel<<<dim3(512), 1024, 0, stream>>>(out2, k3, fcw, fcb, out);
}

// Round 7
// 480.837 us; speedup vs baseline: 5.7533x; 5.7533x over previous
//
#include <hip/hip_runtime.h>
#include <math.h>

// ===========================================================================
// Kernel 0: W_eff precompute.  conv3 and FC are both linear =>
//   logits[cls] = sum_{c,yi,xi} in2[c,yi,xi] * W_eff[cls,c,yi,xi] + fcb[cls]
//   W_eff[cls,c,yi,xi] = sum_{o,ki,kj; yo=yi-ki+1 in [0,32), xo=xi-kj+1 in [0,32)}
//                        k3[((c*3+ki)*3+kj)*16+o] * fcw[cls*16384 + o*1024 + yo*32+xo]
// 9216 threads, 6 classes each.
// ===========================================================================
__global__ __launch_bounds__(256) void weff_kernel(
    const float* __restrict__ k3, const float* __restrict__ fcw,
    float* __restrict__ weff)
{
    const int t = blockIdx.x * 256 + threadIdx.x;   // 0..9215
    if (t >= 9216) return;
    const int c  = t >> 10;
    const int yx = t & 1023;
    const int yi = yx >> 5, xi = yx & 31;

    float acc[6] = {0.f, 0.f, 0.f, 0.f, 0.f, 0.f};
#pragma unroll
    for (int ki = 0; ki < 3; ++ki) {
        const int yo = yi - ki + 1;
        if ((unsigned)yo >= 32u) continue;
#pragma unroll
        for (int kj = 0; kj < 3; ++kj) {
            const int xo = xi - kj + 1;
            if ((unsigned)xo >= 32u) continue;
            const float* w3 = &k3[((c * 3 + ki) * 3 + kj) * 16];
            const int fbase = yo * 32 + xo;
#pragma unroll
            for (int o = 0; o < 16; ++o) {
                const float w = w3[o];
#pragma unroll
                for (int cls = 0; cls < 6; ++cls)
                    acc[cls] = fmaf(w, fcw[cls * 16384 + o * 1024 + fbase], acc[cls]);
            }
        }
    }
#pragma unroll
    for (int cls = 0; cls < 6; ++cls)
        weff[cls * 9216 + t] = acc[cls];
}

// ===========================================================================
// Stage 1: conv1(5x5,pad1) + ReLU + BN(eval) + maxpool(3,2,1, zero-pad)
//   in : x [512,3,128,128]   out: out1 [512,5,63,63]
//   w(o,c,ki,kj) = k1[((c*5+ki)*5+kj)*5 + o]   (reference reshape semantics)
// R4 structure (known-good ~255us): single-phase, register-blocked 3x3 conv
// window per thread, full static unroll, no launch-bounds VGPR cap.
// ===========================================================================
__global__ __launch_bounds__(256) void conv1_pool_kernel(
    const float* __restrict__ x, const float* __restrict__ k1,
    const float* __restrict__ gamma, const float* __restrict__ beta,
    float* __restrict__ out1)
{
    const int b    = blockIdx.y;
    const int tile = blockIdx.x;          // 0..15
    const int ty = tile >> 2, tx = tile & 3;
    const int tid = threadIdx.x;

    __shared__ float sIn[3][37][40];      // 17.8 KB

    const int iy0 = 32 * ty - 2, ix0 = 32 * tx - 2;
    for (int idx = tid; idx < 3 * 37 * 37; idx += 256) {
        int c  = idx / 1369;
        int r  = idx - c * 1369;
        int ly = r / 37, lx = r - ly * 37;
        int gy = iy0 + ly, gx = ix0 + lx;
        float v = 0.f;
        if ((unsigned)gy < 128u && (unsigned)gx < 128u)
            v = x[((b * 3 + c) * 128 + gy) * 128 + gx];
        sIn[c][ly][lx] = v;
    }
    __syncthreads();

    const int lpy = tid >> 4, lpx = tid & 15;
    const int py = 16 * ty + lpy, px = 16 * tx + lpx;

    float acc[3][3][5];
#pragma unroll
    for (int r = 0; r < 3; ++r)
#pragma unroll
        for (int p = 0; p < 3; ++p)
#pragma unroll
            for (int o = 0; o < 5; ++o) acc[r][p][o] = 0.f;

#pragma unroll
    for (int c = 0; c < 3; ++c)
#pragma unroll
        for (int ir = 0; ir < 7; ++ir) {
            float iv[7];
#pragma unroll
            for (int j = 0; j < 7; ++j)
                iv[j] = sIn[c][2 * lpy + ir][2 * lpx + j];
#pragma unroll
            for (int ki = 0; ki < 5; ++ki) {
                const int cr = ir - ki;            // compile-time per (ir,ki)
                if (cr >= 0 && cr < 3) {
#pragma unroll
                    for (int kj = 0; kj < 5; ++kj) {
                        const float* w = &k1[((c * 5 + ki) * 5 + kj) * 5];
#pragma unroll
                        for (int cp = 0; cp < 3; ++cp) {
                            float v = iv[cp + kj];
#pragma unroll
                            for (int o = 0; o < 5; ++o)
                                acc[cr][cp][o] = fmaf(v, w[o], acc[cr][cp][o]);
                        }
                    }
                }
            }
        }

    if (py < 63 && px < 63) {
        const float invs = rsqrtf(1.0f + 1e-5f);
        const bool tb = (py == 0), lb = (px == 0);
#pragma unroll
        for (int o = 0; o < 5; ++o) {
            const float sc = gamma[o] * invs, bt = beta[o];
            float m = -3.4e38f;
#pragma unroll
            for (int dy = 0; dy < 3; ++dy)
#pragma unroll
                for (int dx = 0; dx < 3; ++dx) {
                    float v = fmaf(fmaxf(acc[dy][dx][o], 0.f), sc, bt);
                    const bool ok = !(tb && dy == 0) && !(lb && dx == 0);
                    m = ok ? fmaxf(m, v) : m;
                }
            if (tb || lb) m = fmaxf(m, 0.f);      // pool zero-padding
            out1[((b * 5 + o) * 63 + py) * 63 + px] = m;
        }
    }
}

// ===========================================================================
// Stage 2: conv2(3x3,pad1) + ReLU + maxpool(3,2,1)
//   in : out1 [512,5,63,63]  out: out2 [512,9,32,32]
//   w(o,c,ki,kj) = k2[((c*3+ki)*3+kj)*9 + o]
// Same per-thread compute as R4 (known-correct), but FINER blocks for
// latency hiding: 128 threads per block, 8x16 pool tile, LDS 13.7 KB,
// grid 4096 blocks (16/CU vs 8/CU before).
// ===========================================================================
__global__ __launch_bounds__(128) void conv2_pool_kernel(
    const float* __restrict__ in1, const float* __restrict__ k2,
    float* __restrict__ out2)
{
    const int b    = blockIdx.y;
    const int tile = blockIdx.x;          // 0..7
    const int ty = tile >> 1, tx = tile & 1;   // ty: 0..3 (8-row bands), tx: 0..1
    const int tid = threadIdx.x;

    __shared__ float sIn[5][19][36];      // 13.7 KB

    const int iy0 = 16 * ty - 2, ix0 = 32 * tx - 2;
    for (int idx = tid; idx < 5 * 19 * 35; idx += 128) {
        int c  = idx / 665;
        int r  = idx - c * 665;
        int ly = r / 35, lx = r - ly * 35;
        int gy = iy0 + ly, gx = ix0 + lx;
        float v = 0.f;
        if ((unsigned)gy < 63u && (unsigned)gx < 63u)
            v = in1[((b * 5 + c) * 63 + gy) * 63 + gx];
        sIn[c][ly][lx] = v;
    }
    __syncthreads();

    const int lpy = tid >> 4, lpx = tid & 15;   // lpy 0..7, lpx 0..15
    const int py = 8 * ty + lpy, px = 16 * tx + lpx;   // 0..31

    float m[9];
#pragma unroll
    for (int o = 0; o < 9; ++o) m[o] = 0.f;   // relu>=0 and zero pool-pad

#pragma unroll
    for (int cr = 0; cr < 3; ++cr) {
        float acc[3][9];
#pragma unroll
        for (int p = 0; p < 3; ++p)
#pragma unroll
            for (int o = 0; o < 9; ++o) acc[p][o] = 0.f;

#pragma unroll
        for (int c = 0; c < 5; ++c)
#pragma unroll
            for (int ki = 0; ki < 3; ++ki) {
                float iv[5];
#pragma unroll
                for (int j = 0; j < 5; ++j)
                    iv[j] = sIn[c][2 * lpy + cr + ki][2 * lpx + j];
#pragma unroll
                for (int kj = 0; kj < 3; ++kj) {
                    const float* w = &k2[((c * 3 + ki) * 3 + kj) * 9];
#pragma unroll
                    for (int p = 0; p < 3; ++p) {
                        float v = iv[p + kj];
#pragma unroll
                        for (int o = 0; o < 9; ++o)
                            acc[p][o] = fmaf(v, w[o], acc[p][o]);
                    }
                }
            }

        // conv row cy = 2py-1+cr valid iff 0 <= cy < 63
        const int cy = 2 * py - 1 + cr;
        const bool rowok = ((unsigned)cy < 63u);
#pragma unroll
        for (int p = 0; p < 3; ++p) {
            const bool ok = rowok && (p > 0 || px > 0) && (p < 2 || px < 31);
#pragma unroll
            for (int o = 0; o < 9; ++o) {
                float v = fmaxf(acc[p][o], 0.f);      // relu; pads stay 0
                m[o] = ok ? fmaxf(m[o], v) : m[o];
            }
        }
    }

#pragma unroll
    for (int o = 0; o < 9; ++o)
        out2[((b * 9 + o) * 32 + py) * 32 + px] = m[o];
}

// ===========================================================================
// Stage 3: logits = dot(in2_flat[9216], W_eff[cls]) + fcb  ->  softmax.
// One 256-thread block per sample; fully coalesced float4 reads.
// ===========================================================================
__global__ __launch_bounds__(256) void fc_softmax_kernel(
    const float* __restrict__ in2, const float* __restrict__ weff,
    const float* __restrict__ fcb, float* __restrict__ out)
{
    const int b   = blockIdx.x;
    const int tid = threadIdx.x;

    const float4* in4 = (const float4*)(in2 + (size_t)b * 9216);

    float acc[6] = {0.f, 0.f, 0.f, 0.f, 0.f, 0.f};
#pragma unroll
    for (int k = 0; k < 9; ++k) {
        const int e4 = tid + k * 256;          // 0..2303
        float4 v = in4[e4];
#pragma unroll
        for (int cls = 0; cls < 6; ++cls) {
            float4 w = ((const float4*)(weff + cls * 9216))[e4];
            float s = fmaf(v.x, w.x, fmaf(v.y, w.y, fmaf(v.z, w.z, v.w * w.w)));
            acc[cls] += s;
        }
    }

    __shared__ float sRed[4][6];
#pragma unroll
    for (int cls = 0; cls < 6; ++cls) {
        float v = acc[cls];
#pragma unroll
        for (int off = 32; off >= 1; off >>= 1)
            v += __shfl_xor(v, off, 64);
        if ((tid & 63) == 0) sRed[tid >> 6][cls] = v;
    }
    __syncthreads();
    if (tid == 0) {
        float logits[6], mxl = -3.4e38f;
#pragma unroll
        for (int cls = 0; cls < 6; ++cls) {
            float l = sRed[0][cls] + sRed[1][cls] + sRed[2][cls] + sRed[3][cls]
                      + fcb[cls];
            logits[cls] = l;
            mxl = fmaxf(mxl, l);
        }
        float ssum = 0.f;
#pragma unroll
        for (int cls = 0; cls < 6; ++cls) {
            logits[cls] = expf(logits[cls] - mxl);
            ssum += logits[cls];
        }
#pragma unroll
        for (int cls = 0; cls < 6; ++cls)
            out[b * 6 + cls] = logits[cls] / ssum;
    }
}

extern "C" void kernel_launch(void* const* d_in, const int* in_sizes, int n_in,
                              void* d_out, int out_size, void* d_ws, size_t ws_size,
                              hipStream_t stream)
{
    const float* x     = (const float*)d_in[0];
    const float* k1    = (const float*)d_in[1];
    const float* gamma = (const float*)d_in[2];
    const float* beta  = (const float*)d_in[3];
    const float* k2    = (const float*)d_in[4];
    const float* k3    = (const float*)d_in[5];
    const float* fcw   = (const float*)d_in[6];
    const float* fcb   = (const float*)d_in[7];
    float* out = (float*)d_out;

    float* out1 = (float*)d_ws;                       // 512*5*63*63  (40.6 MB)
    float* out2 = out1 + (size_t)512 * 5 * 63 * 63;   // 512*9*32*32  (18.9 MB)
    float* weff = out2 + (size_t)512 * 9 * 32 * 32;   // 6*9216       (0.22 MB)

    weff_kernel<<<dim3(36), 256, 0, stream>>>(k3, fcw, weff);
    conv1_pool_kernel<<<dim3(16, 512), 256, 0, stream>>>(x, k1, gamma, beta, out1);
    conv2_pool_kernel<<<dim3(8, 512), 128, 0, stream>>>(out1, k2, out2);
    fc_softmax_kernel<<<dim3(512), 256, 0, stream>>>(out2, weff, fcb, out);
}